// Round 8
// baseline (212.188 us; speedup 1.0000x reference)
//
#include <hip/hip_runtime.h>
#include <math.h>
#include <stdint.h>

#define B_   2
#define N_   10000
#define E_   160000
#define HID_ 128
#define ED_  32
#define NH_  8
#define HD_  16
#define ROWS_ (B_ * N_)   // 20000

using half2_t = __attribute__((ext_vector_type(2))) _Float16;
using f16x8   = __attribute__((ext_vector_type(8))) _Float16;
using f32x4   = __attribute__((ext_vector_type(4))) float;

__device__ __forceinline__ half2_t f2h2(float a, float b) {
    return __builtin_bit_cast(half2_t, __builtin_amdgcn_cvt_pkrtz(a, b));
}
__device__ __forceinline__ uint32_t pkh2(float a, float b) {
    return __builtin_bit_cast(uint32_t, __builtin_amdgcn_cvt_pkrtz(a, b));
}

// ---------------- CSR build ----------------

__global__ void zero_kernel(int* __restrict__ deg, int* __restrict__ cursor, int n) {
    int i = blockIdx.x * 256 + threadIdx.x;
    if (i < n) { deg[i] = 0; cursor[i] = 0; }
}

__global__ void hist_kernel(const int* __restrict__ ei, int* __restrict__ deg, int E) {
    int e = blockIdx.x * 256 + threadIdx.x;
    if (e < E) atomicAdd(&deg[ei[2 * e + 1]], 1);
}

__global__ __launch_bounds__(256) void scan_kernel(const int* __restrict__ deg,
                                                   int* __restrict__ off, int N) {
    __shared__ int sums[256];
    int t = threadIdx.x;
    int chunk = (N + 255) / 256;
    int s0 = t * chunk, s1 = min(N, s0 + chunk);
    int s = 0;
    for (int i = s0; i < s1; ++i) s += deg[i];
    sums[t] = s;
    __syncthreads();
    if (t == 0) {
        int run = 0;
        for (int i = 0; i < 256; ++i) { int v = sums[i]; sums[i] = run; run += v; }
        off[N] = run;
    }
    __syncthreads();
    int run = sums[t];
    for (int i = s0; i < s1; ++i) { off[i] = run; run += deg[i]; }
}

__global__ void fill_kernel(const int* __restrict__ ei, const int* __restrict__ off,
                            int* __restrict__ cursor, int* __restrict__ csr, int E) {
    int e = blockIdx.x * 256 + threadIdx.x;
    if (e < E) {
        int d = ei[2 * e + 1];
        int p = atomicAdd(&cursor[d], 1);
        csr[off[d] + p] = e;
    }
}

// ---------------- projections: f16 LDS + v_dot2_f32_f16, 2x4 blocking ----------------
// qkvs: 512 cols = [Q | K | V | S], S = h.Ws^T + bs + ba.

#define R_T 32
#define JC2 64
#define LDH2 68   // dwords (=half2) per row: 64 + 4 pad

__global__ __launch_bounds__(256) void qkvs_kernel(
    const float* __restrict__ h,
    const float* __restrict__ Wq, const float* __restrict__ bq,
    const float* __restrict__ Wk, const float* __restrict__ bk,
    const float* __restrict__ Wv, const float* __restrict__ bv,
    const float* __restrict__ Ws, const float* __restrict__ bs,
    const float* __restrict__ ba,
    float* __restrict__ Q, float* __restrict__ KV, float* __restrict__ S)
{
    __shared__ uint32_t hs[R_T * LDH2];
    __shared__ uint32_t wsm[JC2 * LDH2];
    __shared__ float bsm[512];

    int tid = threadIdx.x;
    int row0 = blockIdx.x * R_T;

    for (int f = tid; f < 512; f += 256) {
        float v;
        if (f < 128) v = bq[f];
        else if (f < 256) v = bk[f - 128];
        else if (f < 384) v = bv[f - 256];
        else v = bs[f - 384] + ba[f - 384];
        bsm[f] = v;
    }

    for (int f = tid; f < R_T * 32; f += 256) {
        int r = f >> 5, c4 = f & 31;
        float4 hv = *(const float4*)(h + (long)(row0 + r) * HID_ + c4 * 4);
        hs[r * LDH2 + c4 * 2]     = pkh2(hv.x, hv.y);
        hs[r * LDH2 + c4 * 2 + 1] = pkh2(hv.z, hv.w);
    }

    int rg = tid & 15;
    int cg = tid >> 4;

    for (int jc = 0; jc < 8; ++jc) {
        __syncthreads();
        for (int f = tid; f < JC2 * 32; f += 256) {
            int jr = f >> 5, c4 = f & 31;
            int J = jc * JC2 + jr;
            const float* Wp;
            if (J < 128)      Wp = Wq + (long)J * HID_;
            else if (J < 256) Wp = Wk + (long)(J - 128) * HID_;
            else if (J < 384) Wp = Wv + (long)(J - 256) * HID_;
            else              Wp = Ws + (long)(J - 384) * HID_;
            float4 wv = *(const float4*)(Wp + c4 * 4);
            wsm[jr * LDH2 + c4 * 2]     = pkh2(wv.x, wv.y);
            wsm[jr * LDH2 + c4 * 2 + 1] = pkh2(wv.z, wv.w);
        }
        __syncthreads();

        float acc[2][4];
        #pragma unroll
        for (int r = 0; r < 2; ++r)
            #pragma unroll
            for (int m = 0; m < 4; ++m) acc[r][m] = 0.f;

        #pragma unroll 4
        for (int kk = 0; kk < 16; ++kk) {
            const half2_t* h0 = (const half2_t*)(hs + rg * LDH2 + kk * 4);
            const half2_t* h1 = (const half2_t*)(hs + (rg + 16) * LDH2 + kk * 4);
            const half2_t* w0 = (const half2_t*)(wsm + cg * LDH2 + kk * 4);
            const half2_t* w1 = (const half2_t*)(wsm + (cg + 16) * LDH2 + kk * 4);
            const half2_t* w2 = (const half2_t*)(wsm + (cg + 32) * LDH2 + kk * 4);
            const half2_t* w3 = (const half2_t*)(wsm + (cg + 48) * LDH2 + kk * 4);
            #pragma unroll
            for (int d = 0; d < 4; ++d) {
                half2_t a0 = h0[d], a1 = h1[d];
                half2_t b0 = w0[d], b1 = w1[d], b2 = w2[d], b3 = w3[d];
                acc[0][0] = __builtin_amdgcn_fdot2(a0, b0, acc[0][0], false);
                acc[0][1] = __builtin_amdgcn_fdot2(a0, b1, acc[0][1], false);
                acc[0][2] = __builtin_amdgcn_fdot2(a0, b2, acc[0][2], false);
                acc[0][3] = __builtin_amdgcn_fdot2(a0, b3, acc[0][3], false);
                acc[1][0] = __builtin_amdgcn_fdot2(a1, b0, acc[1][0], false);
                acc[1][1] = __builtin_amdgcn_fdot2(a1, b1, acc[1][1], false);
                acc[1][2] = __builtin_amdgcn_fdot2(a1, b2, acc[1][2], false);
                acc[1][3] = __builtin_amdgcn_fdot2(a1, b3, acc[1][3], false);
            }
        }

        #pragma unroll
        for (int r = 0; r < 2; ++r) {
            long row = row0 + rg + r * 16;
            #pragma unroll
            for (int m = 0; m < 4; ++m) {
                int J = jc * JC2 + cg + m * 16;
                float v = acc[r][m] + bsm[J];
                if (J < 128)      Q[row * 128 + J] = v;
                else if (J < 256) KV[row * 256 + 2 * (J - 128)] = v;
                else if (J < 384) KV[row * 256 + 2 * (J - 256) + 1] = v;
                else              S[row * 128 + (J - 384)] = v;
            }
        }
    }
}

// wa: A[row][128] = X[row] . Wa^T (no bias; folded into S)
__global__ __launch_bounds__(256) void wa_kernel(
    const float* __restrict__ X, const float* __restrict__ Wa, float* __restrict__ A)
{
    __shared__ uint32_t hs[R_T * LDH2];
    __shared__ uint32_t wsm[JC2 * LDH2];

    int tid = threadIdx.x;
    int row0 = blockIdx.x * R_T;

    for (int f = tid; f < R_T * 32; f += 256) {
        int r = f >> 5, c4 = f & 31;
        float4 hv = *(const float4*)(X + (long)(row0 + r) * HID_ + c4 * 4);
        hs[r * LDH2 + c4 * 2]     = pkh2(hv.x, hv.y);
        hs[r * LDH2 + c4 * 2 + 1] = pkh2(hv.z, hv.w);
    }

    int rg = tid & 15;
    int cg = tid >> 4;

    for (int jc = 0; jc < 2; ++jc) {
        __syncthreads();
        for (int f = tid; f < JC2 * 32; f += 256) {
            int jr = f >> 5, c4 = f & 31;
            int J = jc * JC2 + jr;
            float4 wv = *(const float4*)(Wa + (long)J * HID_ + c4 * 4);
            wsm[jr * LDH2 + c4 * 2]     = pkh2(wv.x, wv.y);
            wsm[jr * LDH2 + c4 * 2 + 1] = pkh2(wv.z, wv.w);
        }
        __syncthreads();

        float acc[2][4];
        #pragma unroll
        for (int r = 0; r < 2; ++r)
            #pragma unroll
            for (int m = 0; m < 4; ++m) acc[r][m] = 0.f;

        #pragma unroll 4
        for (int kk = 0; kk < 16; ++kk) {
            const half2_t* h0 = (const half2_t*)(hs + rg * LDH2 + kk * 4);
            const half2_t* h1 = (const half2_t*)(hs + (rg + 16) * LDH2 + kk * 4);
            const half2_t* w0 = (const half2_t*)(wsm + cg * LDH2 + kk * 4);
            const half2_t* w1 = (const half2_t*)(wsm + (cg + 16) * LDH2 + kk * 4);
            const half2_t* w2 = (const half2_t*)(wsm + (cg + 32) * LDH2 + kk * 4);
            const half2_t* w3 = (const half2_t*)(wsm + (cg + 48) * LDH2 + kk * 4);
            #pragma unroll
            for (int d = 0; d < 4; ++d) {
                half2_t a0 = h0[d], a1 = h1[d];
                half2_t b0 = w0[d], b1 = w1[d], b2 = w2[d], b3 = w3[d];
                acc[0][0] = __builtin_amdgcn_fdot2(a0, b0, acc[0][0], false);
                acc[0][1] = __builtin_amdgcn_fdot2(a0, b1, acc[0][1], false);
                acc[0][2] = __builtin_amdgcn_fdot2(a0, b2, acc[0][2], false);
                acc[0][3] = __builtin_amdgcn_fdot2(a0, b3, acc[0][3], false);
                acc[1][0] = __builtin_amdgcn_fdot2(a1, b0, acc[1][0], false);
                acc[1][1] = __builtin_amdgcn_fdot2(a1, b1, acc[1][1], false);
                acc[1][2] = __builtin_amdgcn_fdot2(a1, b2, acc[1][2], false);
                acc[1][3] = __builtin_amdgcn_fdot2(a1, b3, acc[1][3], false);
            }
        }

        #pragma unroll
        for (int r = 0; r < 2; ++r) {
            long row = row0 + rg + r * 16;
            #pragma unroll
            for (int m = 0; m < 4; ++m) {
                int J = jc * JC2 + cg + m * 16;
                A[row * 128 + J] = acc[r][m];
            }
        }
    }
}

// ---------------- DPP 16-lane head reduce ----------------

template <int CTRL>
__device__ __forceinline__ float dpp_add(float x) {
    int y = __builtin_amdgcn_mov_dpp(__float_as_int(x), CTRL, 0xF, 0xF, true);
    return x + __int_as_float(y);
}
__device__ __forceinline__ float hsum16(float p) {
    p = dpp_add<0xB1>(p);   // quad_perm xor1
    p = dpp_add<0x4E>(p);   // quad_perm xor2
    p = dpp_add<0x141>(p);  // row_half_mirror
    p = dpp_add<0x140>(p);  // row_mirror
    return p;
}

// ---------------- edge aggregation: 4 nodes/block, 128 threads, MFMA E-proj ----------------
// Per chunk of 64 edges: Eproj[64][128] = ea_f16[64][32] @ We^T (+be) via
// mfma_f32_16x16x32_f16 (M-tiles 4, N-tiles 8), P staged f16 in LDS.

#define NPB 4
#define CHUNK 64
#define EAS 20    // dwords per staged ea row (16 data + 4 pad; 16B-aligned, 2-way banks max)
#define PSTR 132  // f16 per P row (128 + 4 pad)

__global__ __launch_bounds__(128) void node_kernel(
    const float* __restrict__ edge_attr, const int* __restrict__ ei,
    const float* __restrict__ Q, const float* __restrict__ KV,
    const float* __restrict__ We, const float* __restrict__ be,
    const float* __restrict__ attn_vec,
    const int* __restrict__ off, const int* __restrict__ csr,
    float* __restrict__ agg)
{
    int n0 = blockIdx.x * NPB;
    int b  = blockIdx.y;
    int j  = threadIdx.x;           // 0..127
    int lane = j & 63;
    int wv = j >> 6;
    long bN = (long)b * N_;

    __shared__ int sL[CHUNK];
    __shared__ uint32_t eaF[CHUNK * EAS];
    __shared__ _Float16 P16[CHUNK * PSTR];

    // B-fragments: We rows as row-major [N][K] fragments (loop-invariant, 32 VGPR)
    f16x8 bfr[8];
    float beC[8];
    {
        int wrow = lane & 15;
        int k0 = (lane >> 4) * 8;
        #pragma unroll
        for (int nt = 0; nt < 8; ++nt) {
            const float* Wr = We + (long)(nt * 16 + wrow) * ED_ + k0;
            float4 w0 = *(const float4*)(Wr);
            float4 w1 = *(const float4*)(Wr + 4);
            union { f16x8 v; uint32_t u[4]; } bu;
            bu.u[0] = pkh2(w0.x, w0.y);
            bu.u[1] = pkh2(w0.z, w0.w);
            bu.u[2] = pkh2(w1.x, w1.y);
            bu.u[3] = pkh2(w1.z, w1.w);
            bfr[nt] = bu.v;
            beC[nt] = be[nt * 16 + wrow];
        }
    }
    float avj = attn_vec[j];

    float q0 = Q[(bN + n0 + 0) * 128 + j];
    float q1 = Q[(bN + n0 + 1) * 128 + j];
    float q2 = Q[(bN + n0 + 2) * 128 + j];
    float q3 = Q[(bN + n0 + 3) * 128 + j];

    int o0 = off[n0];
    int c1 = off[n0 + 1] - o0, c2 = off[n0 + 2] - o0,
        c3 = off[n0 + 3] - o0, c4_ = off[n0 + 4] - o0;
    int total = c4_;

    const float* eab = edge_attr + (long)b * E_ * ED_;
    const float* KVb = KV + bN * 256;

    float acc0 = 0.f, den0 = 0.f, acc1 = 0.f, den1 = 0.f;
    float acc2 = 0.f, den2 = 0.f, acc3 = 0.f, den3 = 0.f;

    auto edge_body = [&](int i, float qg, float& accg, float& deng) {
        int s = sL[i];
        float2 kv = *(const float2*)(KVb + (long)s * 256 + 2 * j);
        float ej = (float)P16[i * PSTR + j];
        float y = qg + kv.x + ej;
        float t = 1.f - 2.f * __builtin_amdgcn_rcpf(__expf(2.f * y) + 1.f);
        float p = hsum16(t * avj);
        float ex = __expf(p * 0.25f);
        deng += ex;
        accg += ex * (kv.y + ej);
    };

    auto range_loop = [&](int lo, int hi, float qg, float& accg, float& deng) {
        int i = lo;
        for (; i + 3 < hi; i += 4) {
            edge_body(i, qg, accg, deng);
            edge_body(i + 1, qg, accg, deng);
            edge_body(i + 2, qg, accg, deng);
            edge_body(i + 3, qg, accg, deng);
        }
        for (; i < hi; ++i) edge_body(i, qg, accg, deng);
    };

    for (int tau = 0; tau < total; tau += CHUNK) {
        int rows = min(total - tau, CHUNK);
        __syncthreads();   // eaF/P16/sL safe to overwrite
        for (int t = j; t < rows; t += 128) {
            int e = csr[o0 + tau + t];
            sL[t] = ei[2 * e];
        }
        for (int idx = j; idx < rows * 8; idx += 128) {
            int r = idx >> 3, c = idx & 7;
            int e = csr[o0 + tau + r];   // L1-hot re-read
            float4 f = *(const float4*)(eab + (long)e * ED_ + c * 4);
            uint2 pk;
            pk.x = pkh2(f.x, f.y);
            pk.y = pkh2(f.z, f.w);
            *(uint2*)(&eaF[r * EAS + 2 * c]) = pk;
        }
        __syncthreads();   // staging done -> MFMA

        // E-projection: 2 M-tiles per wave x 8 N-tiles
        #pragma unroll
        for (int m = 0; m < 2; ++m) {
            int mt = wv * 2 + m;
            int arow = mt * 16 + (lane & 15);
            const f16x8 a = *(const f16x8*)(eaF + arow * EAS + (lane >> 4) * 4);
            int prow = mt * 16 + (lane >> 4) * 4;
            #pragma unroll
            for (int nt = 0; nt < 8; ++nt) {
                f32x4 cfr = { beC[nt], beC[nt], beC[nt], beC[nt] };
                f32x4 d = __builtin_amdgcn_mfma_f32_16x16x32_f16(a, bfr[nt], cfr, 0, 0, 0);
                int pcol = nt * 16 + (lane & 15);
                P16[(prow + 0) * PSTR + pcol] = (_Float16)d[0];
                P16[(prow + 1) * PSTR + pcol] = (_Float16)d[1];
                P16[(prow + 2) * PSTR + pcol] = (_Float16)d[2];
                P16[(prow + 3) * PSTR + pcol] = (_Float16)d[3];
            }
        }
        __syncthreads();   // P16 ready -> edge loop

        range_loop(max(0 - tau, 0),   min(c1 - tau, rows), q0, acc0, den0);
        range_loop(max(c1 - tau, 0),  min(c2 - tau, rows), q1, acc1, den1);
        range_loop(max(c2 - tau, 0),  min(c3 - tau, rows), q2, acc2, den2);
        range_loop(max(c3 - tau, 0),  min(c4_ - tau, rows), q3, acc3, den3);
    }

    agg[(bN + n0 + 0) * 128 + j] = (c1 > 0)   ? acc0 * __builtin_amdgcn_rcpf(den0) : 0.f;
    agg[(bN + n0 + 1) * 128 + j] = (c2 > c1)  ? acc1 * __builtin_amdgcn_rcpf(den1) : 0.f;
    agg[(bN + n0 + 2) * 128 + j] = (c3 > c2)  ? acc2 * __builtin_amdgcn_rcpf(den2) : 0.f;
    agg[(bN + n0 + 3) * 128 + j] = (c4_ > c3) ? acc3 * __builtin_amdgcn_rcpf(den3) : 0.f;
}

// ---------------- final: x = h + gelu(S + A); LayerNorm ----------------

__global__ __launch_bounds__(128) void final_kernel(
    const float* __restrict__ h, const float* __restrict__ S, const float* __restrict__ A,
    const float* __restrict__ ln_g, const float* __restrict__ ln_b,
    float* __restrict__ out)
{
    long row = blockIdx.x;
    int j = threadIdx.x;
    __shared__ float red[4];

    float upd = S[row * 128 + j] + A[row * 128 + j];
    float ge = 0.5f * upd * (1.f + erff(upd * 0.70710678118654752f));
    float x = h[row * 128 + j] + ge;

    float s = x, s2 = x * x;
    #pragma unroll
    for (int m = 1; m < 64; m <<= 1) { s += __shfl_xor(s, m); s2 += __shfl_xor(s2, m); }
    int wv = j >> 6;
    if ((j & 63) == 0) { red[wv] = s; red[2 + wv] = s2; }
    __syncthreads();
    float Sm = red[0] + red[1], S2m = red[2] + red[3];
    float mu = Sm * (1.f / 128.f);
    float var = S2m * (1.f / 128.f) - mu * mu;
    out[row * 128 + j] = (x - mu) * rsqrtf(var + 1e-5f) * ln_g[j] + ln_b[j];
}

// ---------------- launch ----------------

extern "C" void kernel_launch(void* const* d_in, const int* in_sizes, int n_in,
                              void* d_out, int out_size, void* d_ws, size_t ws_size,
                              hipStream_t stream) {
    const float* h         = (const float*)d_in[0];
    const float* edge_attr = (const float*)d_in[1];
    const int*   ei        = (const int*)  d_in[2];
    const float* Wq = (const float*)d_in[3];
    const float* bq = (const float*)d_in[4];
    const float* Wk = (const float*)d_in[5];
    const float* bk = (const float*)d_in[6];
    const float* Wv = (const float*)d_in[7];
    const float* bv = (const float*)d_in[8];
    const float* We = (const float*)d_in[9];
    const float* be = (const float*)d_in[10];
    const float* attn_vec = (const float*)d_in[11];
    const float* Ws = (const float*)d_in[12];
    const float* bs = (const float*)d_in[13];
    const float* Wa = (const float*)d_in[14];
    const float* ba = (const float*)d_in[15];
    const float* ln_g = (const float*)d_in[16];
    const float* ln_b = (const float*)d_in[17];
    float* out = (float*)d_out;

    size_t p = 0;
    auto alloc = [&](size_t bytes) { size_t r = p; p += (bytes + 255) & ~(size_t)255; return r; };
    char* ws = (char*)d_ws;
    float* Q    = (float*)(ws + alloc((size_t)ROWS_ * 128 * 4));   // reused as A after node_kernel
    float* KV   = (float*)(ws + alloc((size_t)ROWS_ * 256 * 4));
    float* S    = (float*)(ws + alloc((size_t)ROWS_ * 128 * 4));
    float* agg  = (float*)(ws + alloc((size_t)ROWS_ * 128 * 4));
    int* deg    = (int*)(ws + alloc((size_t)N_ * 4));
    int* cursor = (int*)(ws + alloc((size_t)N_ * 4));
    int* off    = (int*)(ws + alloc((size_t)(N_ + 1) * 4));
    int* csr    = (int*)(ws + alloc((size_t)E_ * 4));
    float* A = Q;   // alias: Q dead after node_kernel
    (void)ws_size;

    zero_kernel<<<(N_ + 255) / 256, 256, 0, stream>>>(deg, cursor, N_);
    hist_kernel<<<(E_ + 255) / 256, 256, 0, stream>>>(ei, deg, E_);
    scan_kernel<<<1, 256, 0, stream>>>(deg, off, N_);
    fill_kernel<<<(E_ + 255) / 256, 256, 0, stream>>>(ei, off, cursor, csr, E_);

    qkvs_kernel<<<ROWS_ / R_T, 256, 0, stream>>>(h, Wq, bq, Wk, bk, Wv, bv, Ws, bs, ba,
                                                 Q, KV, S);

    dim3 grid(N_ / NPB, B_);
    node_kernel<<<grid, 128, 0, stream>>>(edge_attr, ei, Q, KV, We, be, attn_vec,
                                          off, csr, agg);

    wa_kernel<<<ROWS_ / R_T, 256, 0, stream>>>(agg, Wa, A);

    final_kernel<<<ROWS_, 128, 0, stream>>>(h, S, A, ln_g, ln_b, out);
}

// Round 9
// 176.620 us; speedup vs baseline: 1.2014x; 1.2014x over previous
//
#include <hip/hip_runtime.h>
#include <math.h>
#include <stdint.h>

#define B_   2
#define N_   10000
#define E_   160000
#define HID_ 128
#define ED_  32
#define NH_  8
#define HD_  16
#define ROWS_ (B_ * N_)   // 20000

using half2_t = __attribute__((ext_vector_type(2))) _Float16;
using f16x8   = __attribute__((ext_vector_type(8))) _Float16;
using f32x4   = __attribute__((ext_vector_type(4))) float;

__device__ __forceinline__ half2_t f2h2(float a, float b) {
    return __builtin_bit_cast(half2_t, __builtin_amdgcn_cvt_pkrtz(a, b));
}
__device__ __forceinline__ uint32_t pkh2(float a, float b) {
    return __builtin_bit_cast(uint32_t, __builtin_amdgcn_cvt_pkrtz(a, b));
}

// ---------------- CSR build ----------------

__global__ void zero_kernel(int* __restrict__ deg, int* __restrict__ cursor, int n) {
    int i = blockIdx.x * 256 + threadIdx.x;
    if (i < n) { deg[i] = 0; cursor[i] = 0; }
}

__global__ void hist_kernel(const int* __restrict__ ei, int* __restrict__ deg, int E) {
    int e = blockIdx.x * 256 + threadIdx.x;
    if (e < E) atomicAdd(&deg[ei[2 * e + 1]], 1);
}

__global__ __launch_bounds__(256) void scan_kernel(const int* __restrict__ deg,
                                                   int* __restrict__ off, int N) {
    __shared__ int sums[256];
    int t = threadIdx.x;
    int chunk = (N + 255) / 256;
    int s0 = t * chunk, s1 = min(N, s0 + chunk);
    int s = 0;
    for (int i = s0; i < s1; ++i) s += deg[i];
    sums[t] = s;
    __syncthreads();
    if (t == 0) {
        int run = 0;
        for (int i = 0; i < 256; ++i) { int v = sums[i]; sums[i] = run; run += v; }
        off[N] = run;
    }
    __syncthreads();
    int run = sums[t];
    for (int i = s0; i < s1; ++i) { off[i] = run; run += deg[i]; }
}

__global__ void fill_kernel(const int* __restrict__ ei, const int* __restrict__ off,
                            int* __restrict__ cursor, int* __restrict__ csr, int E) {
    int e = blockIdx.x * 256 + threadIdx.x;
    if (e < E) {
        int d = ei[2 * e + 1];
        int p = atomicAdd(&cursor[d], 1);
        csr[off[d] + p] = e;
    }
}

// ---------------- MFMA projection GEMMs ----------------
// qkvs: out 512 cols = [Q | K | V | S], S = h.Ws^T + bs + ba.
// Tile: 64 rows x 128 cols per 256-thread block; A,W staged f16 in LDS.

#define GM 64
#define LDA 68   // dwords per staged row (64 data + 4 pad) -> 2-way bank alias max

__global__ __launch_bounds__(256) void qkvs_kernel(
    const float* __restrict__ h,
    const float* __restrict__ Wq, const float* __restrict__ bq,
    const float* __restrict__ Wk, const float* __restrict__ bk,
    const float* __restrict__ Wv, const float* __restrict__ bv,
    const float* __restrict__ Ws, const float* __restrict__ bs,
    const float* __restrict__ ba,
    float* __restrict__ Q, float* __restrict__ KV, float* __restrict__ S)
{
    __shared__ uint32_t As[GM * LDA];     // 17408 B
    __shared__ uint32_t Bs[128 * LDA];    // 34816 B
    __shared__ float bsm[128];

    int tid = threadIdx.x;
    int lane = tid & 63;
    int wave = tid >> 6;
    int row0 = blockIdx.x * GM;
    int J0 = blockIdx.y * 128;

    if (tid < 128) {
        int J = J0 + tid;
        float v;
        if (J < 128)      v = bq[J];
        else if (J < 256) v = bk[J - 128];
        else if (J < 384) v = bv[J - 256];
        else              v = bs[J - 384] + ba[J - 384];
        bsm[tid] = v;
    }

    for (int f = tid; f < GM * 32; f += 256) {
        int r = f >> 5, c4 = f & 31;
        long row = row0 + r;
        float4 hv = (row < ROWS_) ? *(const float4*)(h + row * HID_ + c4 * 4)
                                  : make_float4(0.f, 0.f, 0.f, 0.f);
        As[r * LDA + c4 * 2]     = pkh2(hv.x, hv.y);
        As[r * LDA + c4 * 2 + 1] = pkh2(hv.z, hv.w);
    }
    for (int f = tid; f < 128 * 32; f += 256) {
        int jr = f >> 5, c4 = f & 31;
        int J = J0 + jr;
        const float* Wp;
        if (J < 128)      Wp = Wq + (long)J * HID_;
        else if (J < 256) Wp = Wk + (long)(J - 128) * HID_;
        else if (J < 384) Wp = Wv + (long)(J - 256) * HID_;
        else              Wp = Ws + (long)(J - 384) * HID_;
        float4 wv = *(const float4*)(Wp + c4 * 4);
        Bs[jr * LDA + c4 * 2]     = pkh2(wv.x, wv.y);
        Bs[jr * LDA + c4 * 2 + 1] = pkh2(wv.z, wv.w);
    }
    __syncthreads();

    f32x4 acc[8];
    #pragma unroll
    for (int nt = 0; nt < 8; ++nt) {
        float c = bsm[nt * 16 + (lane & 15)];
        acc[nt] = (f32x4){ c, c, c, c };
    }

    int ar = wave * 16 + (lane & 15);
    #pragma unroll
    for (int ks = 0; ks < 4; ++ks) {
        f16x8 a = *(const f16x8*)(As + ar * LDA + ks * 16 + (lane >> 4) * 4);
        #pragma unroll
        for (int nt = 0; nt < 8; ++nt) {
            f16x8 b = *(const f16x8*)(Bs + (nt * 16 + (lane & 15)) * LDA + ks * 16 + (lane >> 4) * 4);
            acc[nt] = __builtin_amdgcn_mfma_f32_16x16x32_f16(a, b, acc[nt], 0, 0, 0);
        }
    }

    #pragma unroll
    for (int nt = 0; nt < 8; ++nt) {
        int J = J0 + nt * 16 + (lane & 15);
        long rbase = row0 + wave * 16 + (lane >> 4) * 4;
        #pragma unroll
        for (int r = 0; r < 4; ++r) {
            long row = rbase + r;
            if (row < ROWS_) {
                float v = acc[nt][r];
                if (J < 128)      Q[row * 128 + J] = v;
                else if (J < 256) KV[row * 256 + 2 * (J - 128)] = v;
                else if (J < 384) KV[row * 256 + 2 * (J - 256) + 1] = v;
                else              S[row * 128 + (J - 384)] = v;
            }
        }
    }
}

// wa: A[row][128] = X[row] . Wa^T  (bias folded into S)
__global__ __launch_bounds__(256) void wa_kernel(
    const float* __restrict__ X, const float* __restrict__ Wa, float* __restrict__ A)
{
    __shared__ uint32_t As[GM * LDA];
    __shared__ uint32_t Bs[128 * LDA];

    int tid = threadIdx.x;
    int lane = tid & 63;
    int wave = tid >> 6;
    int row0 = blockIdx.x * GM;

    for (int f = tid; f < GM * 32; f += 256) {
        int r = f >> 5, c4 = f & 31;
        long row = row0 + r;
        float4 hv = (row < ROWS_) ? *(const float4*)(X + row * HID_ + c4 * 4)
                                  : make_float4(0.f, 0.f, 0.f, 0.f);
        As[r * LDA + c4 * 2]     = pkh2(hv.x, hv.y);
        As[r * LDA + c4 * 2 + 1] = pkh2(hv.z, hv.w);
    }
    for (int f = tid; f < 128 * 32; f += 256) {
        int jr = f >> 5, c4 = f & 31;
        float4 wv = *(const float4*)(Wa + (long)jr * HID_ + c4 * 4);
        Bs[jr * LDA + c4 * 2]     = pkh2(wv.x, wv.y);
        Bs[jr * LDA + c4 * 2 + 1] = pkh2(wv.z, wv.w);
    }
    __syncthreads();

    f32x4 acc[8];
    #pragma unroll
    for (int nt = 0; nt < 8; ++nt) acc[nt] = (f32x4){ 0.f, 0.f, 0.f, 0.f };

    int ar = wave * 16 + (lane & 15);
    #pragma unroll
    for (int ks = 0; ks < 4; ++ks) {
        f16x8 a = *(const f16x8*)(As + ar * LDA + ks * 16 + (lane >> 4) * 4);
        #pragma unroll
        for (int nt = 0; nt < 8; ++nt) {
            f16x8 b = *(const f16x8*)(Bs + (nt * 16 + (lane & 15)) * LDA + ks * 16 + (lane >> 4) * 4);
            acc[nt] = __builtin_amdgcn_mfma_f32_16x16x32_f16(a, b, acc[nt], 0, 0, 0);
        }
    }

    #pragma unroll
    for (int nt = 0; nt < 8; ++nt) {
        int J = nt * 16 + (lane & 15);
        long rbase = row0 + wave * 16 + (lane >> 4) * 4;
        #pragma unroll
        for (int r = 0; r < 4; ++r) {
            long row = rbase + r;
            if (row < ROWS_) A[row * 128 + J] = acc[nt][r];
        }
    }
}

// ---------------- DPP 16-lane head reduce ----------------

template <int CTRL>
__device__ __forceinline__ float dpp_add(float x) {
    int y = __builtin_amdgcn_mov_dpp(__float_as_int(x), CTRL, 0xF, 0xF, true);
    return x + __int_as_float(y);
}
__device__ __forceinline__ float hsum16(float p) {
    p = dpp_add<0xB1>(p);   // quad_perm xor1
    p = dpp_add<0x4E>(p);   // quad_perm xor2
    p = dpp_add<0x141>(p);  // row_half_mirror
    p = dpp_add<0x140>(p);  // row_mirror
    return p;
}

// ---------------- edge aggregation (R7-proven): 4 nodes/block, 128 threads ----------------

#define NPB 4
#define CHUNK 96
#define EAS 20   // dwords per staged ea row (16 data + 4 pad)

__global__ __launch_bounds__(128) void node_kernel(
    const float* __restrict__ edge_attr, const int* __restrict__ ei,
    const float* __restrict__ Q, const float* __restrict__ KV,
    const float* __restrict__ We, const float* __restrict__ be,
    const float* __restrict__ attn_vec,
    const int* __restrict__ off, const int* __restrict__ csr,
    float* __restrict__ agg)
{
    int n0 = blockIdx.x * NPB;
    int b  = blockIdx.y;
    int j  = threadIdx.x;           // 0..127
    long bN = (long)b * N_;

    __shared__ int sL[CHUNK];
    __shared__ uint32_t eaL[CHUNK * EAS];

    half2_t we16[16];
    {
        const float4* We4 = (const float4*)(We + (long)j * ED_);
        #pragma unroll
        for (int c = 0; c < 8; ++c) {
            float4 w = We4[c];
            we16[2 * c]     = f2h2(w.x, w.y);
            we16[2 * c + 1] = f2h2(w.z, w.w);
        }
    }
    float bej = be[j];
    float avj = attn_vec[j];

    float q0 = Q[(bN + n0 + 0) * 128 + j];
    float q1 = Q[(bN + n0 + 1) * 128 + j];
    float q2 = Q[(bN + n0 + 2) * 128 + j];
    float q3 = Q[(bN + n0 + 3) * 128 + j];

    int o0 = off[n0];
    int c1 = off[n0 + 1] - o0, c2 = off[n0 + 2] - o0,
        c3 = off[n0 + 3] - o0, c4_ = off[n0 + 4] - o0;
    int total = c4_;

    const float* eab = edge_attr + (long)b * E_ * ED_;
    const float* KVb = KV + bN * 256;

    float acc0 = 0.f, den0 = 0.f, acc1 = 0.f, den1 = 0.f;
    float acc2 = 0.f, den2 = 0.f, acc3 = 0.f, den3 = 0.f;

    auto edge_body = [&](int i, float qg, float& accg, float& deng) {
        int s = sL[i];
        float2 kv = *(const float2*)(KVb + (long)s * 256 + 2 * j);
        float ej = bej;
        const half2_t* ea = (const half2_t*)(eaL + i * EAS);
        #pragma unroll
        for (int c = 0; c < 16; ++c)
            ej = __builtin_amdgcn_fdot2(we16[c], ea[c], ej, false);
        float y = qg + kv.x + ej;
        float t = 1.f - 2.f * __builtin_amdgcn_rcpf(__expf(2.f * y) + 1.f);
        float p = hsum16(t * avj);
        float ex = __expf(p * 0.25f);
        deng += ex;
        accg += ex * (kv.y + ej);
    };

    auto range_loop = [&](int lo, int hi, float qg, float& accg, float& deng) {
        int i = lo;
        for (; i + 3 < hi; i += 4) {
            edge_body(i, qg, accg, deng);
            edge_body(i + 1, qg, accg, deng);
            edge_body(i + 2, qg, accg, deng);
            edge_body(i + 3, qg, accg, deng);
        }
        for (; i < hi; ++i) edge_body(i, qg, accg, deng);
    };

    for (int tau = 0; tau < total; tau += CHUNK) {
        int rows = min(total - tau, CHUNK);
        __syncthreads();
        for (int t = j; t < rows; t += 128) {
            int e = csr[o0 + tau + t];
            sL[t] = ei[2 * e];
        }
        for (int idx = j; idx < rows * 8; idx += 128) {
            int r = idx >> 3, c = idx & 7;
            int e = csr[o0 + tau + r];
            float4 f = *(const float4*)(eab + (long)e * ED_ + c * 4);
            eaL[r * EAS + 2 * c]     = pkh2(f.x, f.y);
            eaL[r * EAS + 2 * c + 1] = pkh2(f.z, f.w);
        }
        __syncthreads();

        range_loop(max(0 - tau, 0),   min(c1 - tau, rows), q0, acc0, den0);
        range_loop(max(c1 - tau, 0),  min(c2 - tau, rows), q1, acc1, den1);
        range_loop(max(c2 - tau, 0),  min(c3 - tau, rows), q2, acc2, den2);
        range_loop(max(c3 - tau, 0),  min(c4_ - tau, rows), q3, acc3, den3);
    }

    agg[(bN + n0 + 0) * 128 + j] = (c1 > 0)   ? acc0 * __builtin_amdgcn_rcpf(den0) : 0.f;
    agg[(bN + n0 + 1) * 128 + j] = (c2 > c1)  ? acc1 * __builtin_amdgcn_rcpf(den1) : 0.f;
    agg[(bN + n0 + 2) * 128 + j] = (c3 > c2)  ? acc2 * __builtin_amdgcn_rcpf(den2) : 0.f;
    agg[(bN + n0 + 3) * 128 + j] = (c4_ > c3) ? acc3 * __builtin_amdgcn_rcpf(den3) : 0.f;
}

// ---------------- final: x = h + gelu(S + A); LayerNorm ----------------

__global__ __launch_bounds__(128) void final_kernel(
    const float* __restrict__ h, const float* __restrict__ S, const float* __restrict__ A,
    const float* __restrict__ ln_g, const float* __restrict__ ln_b,
    float* __restrict__ out)
{
    long row = blockIdx.x;
    int j = threadIdx.x;
    __shared__ float red[4];

    float upd = S[row * 128 + j] + A[row * 128 + j];
    float ge = 0.5f * upd * (1.f + erff(upd * 0.70710678118654752f));
    float x = h[row * 128 + j] + ge;

    float s = x, s2 = x * x;
    #pragma unroll
    for (int m = 1; m < 64; m <<= 1) { s += __shfl_xor(s, m); s2 += __shfl_xor(s2, m); }
    int wv = j >> 6;
    if ((j & 63) == 0) { red[wv] = s; red[2 + wv] = s2; }
    __syncthreads();
    float Sm = red[0] + red[1], S2m = red[2] + red[3];
    float mu = Sm * (1.f / 128.f);
    float var = S2m * (1.f / 128.f) - mu * mu;
    out[row * 128 + j] = (x - mu) * rsqrtf(var + 1e-5f) * ln_g[j] + ln_b[j];
}

// ---------------- launch ----------------

extern "C" void kernel_launch(void* const* d_in, const int* in_sizes, int n_in,
                              void* d_out, int out_size, void* d_ws, size_t ws_size,
                              hipStream_t stream) {
    const float* h         = (const float*)d_in[0];
    const float* edge_attr = (const float*)d_in[1];
    const int*   ei        = (const int*)  d_in[2];
    const float* Wq = (const float*)d_in[3];
    const float* bq = (const float*)d_in[4];
    const float* Wk = (const float*)d_in[5];
    const float* bk = (const float*)d_in[6];
    const float* Wv = (const float*)d_in[7];
    const float* bv = (const float*)d_in[8];
    const float* We = (const float*)d_in[9];
    const float* be = (const float*)d_in[10];
    const float* attn_vec = (const float*)d_in[11];
    const float* Ws = (const float*)d_in[12];
    const float* bs = (const float*)d_in[13];
    const float* Wa = (const float*)d_in[14];
    const float* ba = (const float*)d_in[15];
    const float* ln_g = (const float*)d_in[16];
    const float* ln_b = (const float*)d_in[17];
    float* out = (float*)d_out;

    size_t p = 0;
    auto alloc = [&](size_t bytes) { size_t r = p; p += (bytes + 255) & ~(size_t)255; return r; };
    char* ws = (char*)d_ws;
    float* Q    = (float*)(ws + alloc((size_t)ROWS_ * 128 * 4));   // reused as A after node_kernel
    float* KV   = (float*)(ws + alloc((size_t)ROWS_ * 256 * 4));
    float* S    = (float*)(ws + alloc((size_t)ROWS_ * 128 * 4));
    float* agg  = (float*)(ws + alloc((size_t)ROWS_ * 128 * 4));
    int* deg    = (int*)(ws + alloc((size_t)N_ * 4));
    int* cursor = (int*)(ws + alloc((size_t)N_ * 4));
    int* off    = (int*)(ws + alloc((size_t)(N_ + 1) * 4));
    int* csr    = (int*)(ws + alloc((size_t)E_ * 4));
    float* A = Q;   // alias: Q dead after node_kernel
    (void)ws_size;

    zero_kernel<<<(N_ + 255) / 256, 256, 0, stream>>>(deg, cursor, N_);
    hist_kernel<<<(E_ + 255) / 256, 256, 0, stream>>>(ei, deg, E_);
    scan_kernel<<<1, 256, 0, stream>>>(deg, off, N_);
    fill_kernel<<<(E_ + 255) / 256, 256, 0, stream>>>(ei, off, cursor, csr, E_);

    dim3 ggrid((ROWS_ + GM - 1) / GM, 4);
    qkvs_kernel<<<ggrid, 256, 0, stream>>>(h, Wq, bq, Wk, bk, Wv, bv, Ws, bs, ba,
                                           Q, KV, S);

    dim3 grid(N_ / NPB, B_);
    node_kernel<<<grid, 128, 0, stream>>>(edge_attr, ei, Q, KV, We, be, attn_vec,
                                          off, csr, agg);

    dim3 wgrid((ROWS_ + GM - 1) / GM, 1);
    wa_kernel<<<wgrid, 256, 0, stream>>>(agg, Wa, A);

    final_kernel<<<ROWS_, 128, 0, stream>>>(h, S, A, ln_g, ln_b, out);
}